// Round 11
// baseline (67.127 us; speedup 1.0000x reference)
//
#include <hip/hip_runtime.h>
#include <hip/hip_bf16.h>
#include <stdint.h>

#define B_  32
#define S_  4096
#define D_  64
#define DK_ 256

typedef float f32x4 __attribute__((ext_vector_type(4)));
typedef short s16x8 __attribute__((ext_vector_type(8)));
typedef uint32_t u32x4 __attribute__((ext_vector_type(4)));

static __device__ __forceinline__ uint16_t f2bf(float f) {
    union { float f; uint32_t u; } x; x.f = f;
    uint32_t u = x.u;
    u += 0x7FFFu + ((u >> 16) & 1u);   // RNE
    return (uint16_t)(u >> 16);
}

static __device__ __forceinline__ float bf2f(uint32_t hi16) {
    union { uint32_t u; float f; } x; x.u = hi16;
    return x.f;
}

static __device__ __forceinline__ uint32_t pk2(float a, float b) {
    __hip_bfloat162 h = __float22bfloat162_rn(float2{a, b});
    union { __hip_bfloat162 h; uint32_t u; } c; c.h = h;
    return c.u;
}

static __device__ __forceinline__ void gload_lds16(const uint16_t* g, uint16_t* l) {
    __builtin_amdgcn_global_load_lds(
        (const __attribute__((address_space(1))) uint32_t*)g,
        (__attribute__((address_space(3))) uint32_t*)l, 16, 0, 0);
}

// ---------------------------------------------------------------------------
// Pass A1: E_w fp32 -> bf16, pre-swizzled into fragment order (unchanged):
// EwbS[kktile(16)][schunk(128)][lane(64)][e(8)],
//   kk = kktile*16 + (lane&15), s = schunk*32 + (lane>>4)*8 + e.
// ---------------------------------------------------------------------------
__global__ __launch_bounds__(256) void ewcvt(const float* __restrict__ E_w,
                                             uint16_t* __restrict__ EwbS) {
    const int tg     = blockIdx.x * 256 + threadIdx.x;   // 0..131071
    const int l16    = tg & 15;
    const int grp    = (tg >> 4) & 3;
    const int schunk = (tg >> 6) & 127;
    const int kktile = tg >> 13;
    const int kk = kktile*16 + l16;
    const int s  = schunk*32 + grp*8;
    const float4 f0 = *(const float4*)(E_w + (size_t)kk * S_ + s);
    const float4 f1 = *(const float4*)(E_w + (size_t)kk * S_ + s + 4);
    s16x8 o;
    o[0] = (short)f2bf(f0.x); o[1] = (short)f2bf(f0.y);
    o[2] = (short)f2bf(f0.z); o[3] = (short)f2bf(f0.w);
    o[4] = (short)f2bf(f1.x); o[5] = (short)f2bf(f1.y);
    o[6] = (short)f2bf(f1.z); o[7] = (short)f2bf(f1.w);
    *(s16x8*)(EwbS + (size_t)tg * 8) = o;
}

// ---------------------------------------------------------------------------
// Pass B: projection GEMM, attn-v6 pattern: ONE-SHOT x staging (32 KB LDS,
// fragment order), then a BARRIER-FREE inner loop — A fragments loaded
// contiguously from L2-resident EwbS into registers per k-step.
// part_u32[r][d][kkp]: r = (p*32+b)*16+ss, kkp = kk/2.
// grid = 2p * 32b * 16ss = 1024 blocks, 256 threads (4 waves).
// ---------------------------------------------------------------------------
__global__ __launch_bounds__(256, 4) void proj_mfma(
        const uint16_t* __restrict__ EwbS,
        const float* __restrict__ kin, const float* __restrict__ vin,
        uint32_t* __restrict__ part) {
    const int bid = blockIdx.x;
    const int ss = bid & 15;
    const int b  = (bid >> 4) & 31;
    const int p  = bid >> 9;
    const float* x = (p ? vin : kin) + (size_t)b * S_ * D_;
    uint32_t* outp = part + ((size_t)((p*32 + b)*16 + ss)) * 8192;

    // Bx[seg = ks*4 + nt][lane][8]: d = nt*16 + (lane&15),
    // s = ss*256 + ks*32 + (lane>>4)*8 + e   (32 KB)
    __shared__ __align__(16) uint16_t Bx[32 * 512];

    const int tid  = threadIdx.x;
    const int w    = tid >> 6;
    const int lane = tid & 63;
    const int l16  = lane & 15;
    const int grp  = lane >> 4;

    // ---- one-shot x staging: thread owns column d = tid&63, s rows w*8..+7
    // of every 32-s chunk; writes fragment-ordered b128s (same mapping the
    // verified R10 staging used per-iteration, seg index extended by ks).
    {
        const int dcol = tid & 63;
        const float* srcB = x + ((size_t)(ss*256 + w*8)) * D_ + dcol;
        const int boff0 = ((dcol >> 4) << 9) + ((w*16 + (dcol & 15)) << 3);
        #pragma unroll
        for (int ks = 0; ks < 8; ++ks) {
            const float* sB = srcB + (size_t)ks*32*D_;
            float xv[8];
            #pragma unroll
            for (int i = 0; i < 8; ++i) xv[i] = sB[i * D_];
            s16x8 h;
            #pragma unroll
            for (int i = 0; i < 8; ++i) h[i] = (short)f2bf(xv[i]);
            *(s16x8*)&Bx[(ks << 11) + boff0] = h;   // seg (ks*4 + nt)
        }
    }
    __syncthreads();   // the ONLY barrier

    // ---- barrier-free K-loop: A from global (L2-hot, contiguous 16B/lane)
    const uint16_t* aBase = EwbS + ((size_t)(w*4)*128 + ss*8) * 512 + lane*8;
    f32x4 acc[4][4] = {};
    #pragma unroll
    for (int ks = 0; ks < 8; ++ks) {
        s16x8 bf[4];
        #pragma unroll
        for (int nt = 0; nt < 4; ++nt)
            bf[nt] = *(const s16x8*)&Bx[((ks*4 + nt) << 9) + lane*8];
        #pragma unroll
        for (int m = 0; m < 4; ++m) {
            // chunk (kktile = w*4+m, schunk = ss*8+ks)
            const s16x8 af = *(const s16x8*)(aBase + ((size_t)m*128 + ks) * 512);
            #pragma unroll
            for (int nt = 0; nt < 4; ++nt)
                acc[m][nt] = __builtin_amdgcn_mfma_f32_16x16x32_bf16(af, bf[nt], acc[m][nt], 0, 0, 0);
        }
    }

    // ---- epilogue: bf16-pair dword stores, [d][kk] layout (unchanged).
    #pragma unroll
    for (int m = 0; m < 4; ++m) {
        const int kkrow = w*64 + m*16 + grp*4;
        #pragma unroll
        for (int nt = 0; nt < 4; ++nt) {
            const int didx = nt*16 + l16;
            outp[didx*128 + (kkrow >> 1)]     = pk2(acc[m][nt][0], acc[m][nt][1]);
            outp[didx*128 + (kkrow >> 1) + 1] = pk2(acc[m][nt][2], acc[m][nt][3]);
        }
    }
}

// ---------------------------------------------------------------------------
// bias_reduce: sum 16 bf16-pair partials + bias, cvt to bf16.
// Now 256 blocks (32 b x 8 dt, 8 d-rows each) to use the whole device.
// V passes straight through ([d][kk]); K transposed via padded LDS tile.
// ---------------------------------------------------------------------------
__global__ __launch_bounds__(256) void bias_reduce(
        const uint32_t* __restrict__ part, const float* __restrict__ E_b,
        uint16_t* __restrict__ Kbf, uint16_t* __restrict__ Vbf) {
    const int b  = blockIdx.x >> 3;
    const int dt = blockIdx.x & 7;
    const int t  = threadIdx.x;

    __shared__ uint16_t Kt[256][10];   // [kk][d_l 0..7], padded

    const uint32_t* Kp = part + ((size_t)(b*16))      * 8192 + dt*8*128;
    const uint32_t* Vp = part + ((size_t)((32+b)*16)) * 8192 + dt*8*128;

    #pragma unroll
    for (int j = 0; j < 4; ++j) {
        const int idx = j*256 + t;       // 0..1023
        const int d_l = idx >> 7;        // 0..7
        const int kkp = idx & 127;       // 0..127
        float k0 = 0.f, k1 = 0.f, v0 = 0.f, v1 = 0.f;
        #pragma unroll
        for (int s = 0; s < 16; ++s) {
            const uint32_t ku = Kp[(size_t)s*8192 + d_l*128 + kkp];
            const uint32_t vu = Vp[(size_t)s*8192 + d_l*128 + kkp];
            k0 += bf2f(ku << 16);
            k1 += bf2f(ku & 0xffff0000u);
            v0 += bf2f(vu << 16);
            v1 += bf2f(vu & 0xffff0000u);
        }
        const int kk0 = kkp*2;
        const float b0 = E_b[kk0], b1 = E_b[kk0 + 1];
        *(uint32_t*)(Vbf + ((size_t)(b*64 + dt*8 + d_l))*256 + kk0) =
            (uint32_t)f2bf(v0 + b0) | ((uint32_t)f2bf(v1 + b1) << 16);
        Kt[kk0][d_l]     = f2bf(k0 + b0);
        Kt[kk0 + 1][d_l] = f2bf(k1 + b1);
    }
    __syncthreads();

    // K transposed write: thread t = kk row, 8 d values (16B store)
    uint16_t* kout = Kbf + ((size_t)(b*256 + t))*64 + dt*8;
    s16x8 o0;
    #pragma unroll
    for (int i = 0; i < 8; ++i) o0[i] = (short)Kt[t][i];
    *(s16x8*)kout = o0;
}

// ---------------------------------------------------------------------------
// attn v6 (unchanged, verified).
// ---------------------------------------------------------------------------
__global__ __launch_bounds__(512, 4) void attn(
        const float* __restrict__ q,
        const uint16_t* __restrict__ Kbf, const uint16_t* __restrict__ Vbf,
        float* __restrict__ out) {
    const int wg   = blockIdx.x;
    const int st   = wg & 31;
    const int b    = wg >> 5;
    const int tid  = threadIdx.x;
    const int wave = tid >> 6;
    const int lane = tid & 63;
    const int l16  = lane & 15;
    const int grp  = lane >> 4;
    const int s0   = st * 128 + wave * 16;

    __shared__ __align__(16) uint16_t Klds[16384];
    __shared__ __align__(16) uint16_t Vlds[16384];

    const uint16_t* Kb = Kbf + (size_t)b * DK_ * D_;
    const uint16_t* Vb = Vbf + (size_t)b * D_ * DK_;

    #pragma unroll
    for (int i = 0; i < 4; ++i) {
        const int s  = wave*4 + i;
        const int nt = s >> 1, kt = s & 1;
        gload_lds16(Kb + (size_t)(nt*16 + l16) * D_ + kt*32 + grp*8, &Klds[s*512]);
    }
    #pragma unroll
    for (int i = 0; i < 4; ++i) {
        const int s   = wave*4 + i;
        const int kt2 = s >> 2, nt2 = s & 3;
        gload_lds16(Vb + (size_t)(nt2*16 + l16) * DK_ + kt2*32 + grp*8, &Vlds[s*512]);
    }

    s16x8 qb[2];
    {
        const float* qp = q + ((size_t)b * S_ + s0 + l16) * D_;
        #pragma unroll
        for (int kt = 0; kt < 2; ++kt) {
            const int d0 = kt*32 + grp*8;
            const float4 f0 = *(const float4*)(qp + d0);
            const float4 f1 = *(const float4*)(qp + d0 + 4);
            s16x8 a;
            a[0] = (short)f2bf(f0.x * 0.125f);
            a[1] = (short)f2bf(f0.y * 0.125f);
            a[2] = (short)f2bf(f0.z * 0.125f);
            a[3] = (short)f2bf(f0.w * 0.125f);
            a[4] = (short)f2bf(f1.x * 0.125f);
            a[5] = (short)f2bf(f1.y * 0.125f);
            a[6] = (short)f2bf(f1.z * 0.125f);
            a[7] = (short)f2bf(f1.w * 0.125f);
            qb[kt] = a;
        }
    }

    __syncthreads();

    f32x4 acc[16] = {};
    #pragma unroll
    for (int nt = 0; nt < 16; ++nt) {
        #pragma unroll
        for (int kt = 0; kt < 2; ++kt) {
            const s16x8 kf = *(const s16x8*)&Klds[(nt*2 + kt)*512 + lane*8];
            acc[nt] = __builtin_amdgcn_mfma_f32_16x16x32_bf16(kf, qb[kt], acc[nt], 0, 0, 0);
        }
    }

    float sm = 0.f;
    #pragma unroll
    for (int nt = 0; nt < 16; ++nt) {
        #pragma unroll
        for (int r = 0; r < 4; ++r) {
            const float e = __expf(acc[nt][r]);
            acc[nt][r] = e;
            sm += e;
        }
    }
    sm += __shfl_xor(sm, 16);
    sm += __shfl_xor(sm, 32);
    const float inv = 1.f / sm;

    uint32_t pk[16][2];
    #pragma unroll
    for (int nt = 0; nt < 16; ++nt) {
        pk[nt][0] = pk2(acc[nt][0], acc[nt][1]);
        pk[nt][1] = pk2(acc[nt][2], acc[nt][3]);
    }

    float invs[4];
    #pragma unroll
    for (int r = 0; r < 4; ++r) invs[r] = __shfl(inv, grp*4 + r);

    const int sl0 = (((grp << 1) + 0) & 3) * 16 + l16;
    const int sl1 = (((grp << 1) + 1) & 3) * 16 + l16;
    const bool lohalf = (grp < 2);

    f32x4 o[4] = {};
    #pragma unroll
    for (int kt2 = 0; kt2 < 8; ++kt2) {
        union { u32x4 wv; s16x8 h; } u;
        #pragma unroll
        for (int c = 0; c < 4; ++c) {
            const int tt = c & 1;
            const int sl = (c >> 1) ? sl1 : sl0;
            const uint32_t lo = (uint32_t)__shfl((int)pk[2*kt2 + 0][tt], sl);
            const uint32_t hi = (uint32_t)__shfl((int)pk[2*kt2 + 1][tt], sl);
            u.wv[c] = lohalf ? lo : hi;
        }
        #pragma unroll
        for (int nt2 = 0; nt2 < 4; ++nt2) {
            const s16x8 vf = *(const s16x8*)&Vlds[(kt2*4 + nt2)*512 + lane*8];
            o[nt2] = __builtin_amdgcn_mfma_f32_16x16x32_bf16(u.h, vf, o[nt2], 0, 0, 0);
        }
    }

    #pragma unroll
    for (int nt2 = 0; nt2 < 4; ++nt2)
        #pragma unroll
        for (int r = 0; r < 4; ++r)
            out[((size_t)b * S_ + s0 + grp*4 + r) * D_ + nt2*16 + l16] =
                o[nt2][r] * invs[r];
}

extern "C" void kernel_launch(void* const* d_in, const int* in_sizes, int n_in,
                              void* d_out, int out_size, void* d_ws, size_t ws_size,
                              hipStream_t stream) {
    const float* q   = (const float*)d_in[0];
    const float* k   = (const float*)d_in[1];
    const float* v   = (const float*)d_in[2];
    const float* E_w = (const float*)d_in[3];
    const float* E_b = (const float*)d_in[4];
    float* out = (float*)d_out;

    char* ws = (char*)d_ws;
    uint32_t* part = (uint32_t*)(ws);                     // 32 MB bf16-pairs
    uint16_t* Kbf  = (uint16_t*)(ws + (32u << 20));       // 1 MB
    uint16_t* Vbf  = (uint16_t*)(ws + (33u << 20));       // 1 MB
    uint16_t* EwbS = (uint16_t*)(ws + (34u << 20));       // 2 MB swizzled

    ewcvt<<<512, 256, 0, stream>>>(E_w, EwbS);
    proj_mfma<<<1024, 256, 0, stream>>>(EwbS, k, v, part);
    bias_reduce<<<256, 256, 0, stream>>>(part, E_b, Kbf, Vbf);
    attn<<<1024, 512, 0, stream>>>(q, Kbf, Vbf, out);
}

// Round 12
// 65.535 us; speedup vs baseline: 1.0243x; 1.0243x over previous
//
#include <hip/hip_runtime.h>
#include <hip/hip_bf16.h>
#include <stdint.h>

#define B_  32
#define S_  4096
#define D_  64
#define DK_ 256

typedef float f32x4 __attribute__((ext_vector_type(4)));
typedef short s16x8 __attribute__((ext_vector_type(8)));
typedef uint32_t u32x4 __attribute__((ext_vector_type(4)));

static __device__ __forceinline__ uint16_t f2bf(float f) {
    union { float f; uint32_t u; } x; x.f = f;
    uint32_t u = x.u;
    u += 0x7FFFu + ((u >> 16) & 1u);   // RNE
    return (uint16_t)(u >> 16);
}

static __device__ __forceinline__ float bf2f(uint32_t hi16) {
    union { uint32_t u; float f; } x; x.u = hi16;
    return x.f;
}

static __device__ __forceinline__ uint32_t pk2(float a, float b) {
    __hip_bfloat162 h = __float22bfloat162_rn(float2{a, b});
    union { __hip_bfloat162 h; uint32_t u; } c; c.h = h;
    return c.u;
}

static __device__ __forceinline__ void gload_lds16(const uint16_t* g, uint16_t* l) {
    __builtin_amdgcn_global_load_lds(
        (const __attribute__((address_space(1))) uint32_t*)g,
        (__attribute__((address_space(3))) uint32_t*)l, 16, 0, 0);
}

// ---------------------------------------------------------------------------
// Pass A1: E_w fp32 -> bf16, pre-swizzled into fragment order (unchanged):
// EwbS[kktile(16)][schunk(128)][lane(64)][e(8)],
//   kk = kktile*16 + (lane&15), s = schunk*32 + (lane>>4)*8 + e.
// ---------------------------------------------------------------------------
__global__ __launch_bounds__(256) void ewcvt(const float* __restrict__ E_w,
                                             uint16_t* __restrict__ EwbS) {
    const int tg     = blockIdx.x * 256 + threadIdx.x;   // 0..131071
    const int l16    = tg & 15;
    const int grp    = (tg >> 4) & 3;
    const int schunk = (tg >> 6) & 127;
    const int kktile = tg >> 13;
    const int kk = kktile*16 + l16;
    const int s  = schunk*32 + grp*8;
    const float4 f0 = *(const float4*)(E_w + (size_t)kk * S_ + s);
    const float4 f1 = *(const float4*)(E_w + (size_t)kk * S_ + s + 4);
    s16x8 o;
    o[0] = (short)f2bf(f0.x); o[1] = (short)f2bf(f0.y);
    o[2] = (short)f2bf(f0.z); o[3] = (short)f2bf(f0.w);
    o[4] = (short)f2bf(f1.x); o[5] = (short)f2bf(f1.y);
    o[6] = (short)f2bf(f1.z); o[7] = (short)f2bf(f1.w);
    *(s16x8*)(EwbS + (size_t)tg * 8) = o;
}

// ---------------------------------------------------------------------------
// Pass B: projection GEMM, split-K = 4 (K-chunk 1024), 4 super-steps of 256 s
// with double-buffered 32 KB LDS; per super-step: issue next x-loads early,
// compute 8 k-steps (A frags straight from L2-resident EwbS), write next
// buffer, ONE barrier. Partial traffic cut 4x vs R11.
// part_u32[r][d][kkp]: r = (p*32+b)*4+ss.
// grid = 2p * 32b * 4ss = 256 blocks, 256 threads (4 waves, 1 block/CU).
// ---------------------------------------------------------------------------
__global__ __launch_bounds__(256) void proj_mfma(
        const uint16_t* __restrict__ EwbS,
        const float* __restrict__ kin, const float* __restrict__ vin,
        uint32_t* __restrict__ part) {
    const int bid = blockIdx.x;
    const int ss = bid & 3;
    const int b  = (bid >> 2) & 31;
    const int p  = bid >> 7;
    const float* x = (p ? vin : kin) + (size_t)b * S_ * D_;
    uint32_t* outp = part + ((size_t)((p*32 + b)*4 + ss)) * 8192;

    // Bx[buf][seg = ks*4 + nt][lane][8]: d = nt*16 + (lane&15),
    // s(within step) = ks*32 + (lane>>4)*8 + e
    __shared__ __align__(16) uint16_t Bx[2][32 * 512];   // 2 x 32 KB

    const int tid  = threadIdx.x;
    const int w    = tid >> 6;
    const int lane = tid & 63;
    const int l16  = lane & 15;
    const int grp  = lane >> 4;

    // x staging source: thread owns column d = tid&63, s rows w*8..+7 of each
    // 32-s chunk (identical mapping to verified R11 staging).
    const int dcol = tid & 63;
    const float* srcB = x + ((size_t)(ss*1024 + w*8)) * D_ + dcol;
    const int boff0 = ((dcol >> 4) << 9) + ((w*16 + (dcol & 15)) << 3);

    // ---- prologue: stage super-step 0 into buf 0
    #pragma unroll
    for (int ks = 0; ks < 8; ++ks) {
        const float* sB = srcB + (size_t)ks*32*D_;
        float xv[8];
        #pragma unroll
        for (int i = 0; i < 8; ++i) xv[i] = sB[i * D_];
        s16x8 h;
        #pragma unroll
        for (int i = 0; i < 8; ++i) h[i] = (short)f2bf(xv[i]);
        *(s16x8*)&Bx[0][(ks << 11) + boff0] = h;
    }
    __syncthreads();

    const uint16_t* aBase = EwbS + ((size_t)(w*4)*128 + ss*32) * 512 + lane*8;
    f32x4 acc[4][4] = {};

    #pragma unroll
    for (int sup = 0; sup < 4; ++sup) {
        // issue next super-step's 64 x-loads BEFORE compute (latency hides
        // under the 128 MFMAs + A-loads below)
        float xv[64];
        if (sup < 3) {
            const float* sS = srcB + (size_t)(sup+1)*256*D_;
            #pragma unroll
            for (int ks = 0; ks < 8; ++ks)
                #pragma unroll
                for (int i = 0; i < 8; ++i)
                    xv[ks*8 + i] = sS[(size_t)(ks*32 + i) * D_];
        }

        const uint16_t* bufc = &Bx[sup & 1][0];
        #pragma unroll
        for (int ks = 0; ks < 8; ++ks) {
            s16x8 bf[4];
            #pragma unroll
            for (int nt = 0; nt < 4; ++nt)
                bf[nt] = *(const s16x8*)&bufc[((ks*4 + nt) << 9) + lane*8];
            #pragma unroll
            for (int m = 0; m < 4; ++m) {
                // chunk (kktile = w*4+m, schunk = ss*32 + sup*8 + ks)
                const s16x8 af = *(const s16x8*)(aBase + ((size_t)m*128 + sup*8 + ks) * 512);
                #pragma unroll
                for (int nt = 0; nt < 4; ++nt)
                    acc[m][nt] = __builtin_amdgcn_mfma_f32_16x16x32_bf16(af, bf[nt], acc[m][nt], 0, 0, 0);
            }
        }

        if (sup < 3) {
            uint16_t* bufn = &Bx[(sup + 1) & 1][0];
            #pragma unroll
            for (int ks = 0; ks < 8; ++ks) {
                s16x8 h;
                #pragma unroll
                for (int i = 0; i < 8; ++i) h[i] = (short)f2bf(xv[ks*8 + i]);
                *(s16x8*)&bufn[(ks << 11) + boff0] = h;
            }
        }
        __syncthreads();
    }

    // ---- epilogue: bf16-pair dword stores, [d][kk] layout (unchanged).
    #pragma unroll
    for (int m = 0; m < 4; ++m) {
        const int kkrow = w*64 + m*16 + grp*4;
        #pragma unroll
        for (int nt = 0; nt < 4; ++nt) {
            const int didx = nt*16 + l16;
            outp[didx*128 + (kkrow >> 1)]     = pk2(acc[m][nt][0], acc[m][nt][1]);
            outp[didx*128 + (kkrow >> 1) + 1] = pk2(acc[m][nt][2], acc[m][nt][3]);
        }
    }
}

// ---------------------------------------------------------------------------
// bias_reduce: sum 4 bf16-pair partials + bias, cvt to bf16.
// 256 blocks (32 b x 8 dt). V passes through ([d][kk]); K transposed via LDS.
// ---------------------------------------------------------------------------
__global__ __launch_bounds__(256) void bias_reduce(
        const uint32_t* __restrict__ part, const float* __restrict__ E_b,
        uint16_t* __restrict__ Kbf, uint16_t* __restrict__ Vbf) {
    const int b  = blockIdx.x >> 3;
    const int dt = blockIdx.x & 7;
    const int t  = threadIdx.x;

    __shared__ uint16_t Kt[256][10];   // [kk][d_l 0..7], padded

    const uint32_t* Kp = part + ((size_t)(b*4))      * 8192 + dt*8*128;
    const uint32_t* Vp = part + ((size_t)((32+b)*4)) * 8192 + dt*8*128;

    #pragma unroll
    for (int j = 0; j < 4; ++j) {
        const int idx = j*256 + t;       // 0..1023
        const int d_l = idx >> 7;        // 0..7
        const int kkp = idx & 127;       // 0..127
        float k0 = 0.f, k1 = 0.f, v0 = 0.f, v1 = 0.f;
        #pragma unroll
        for (int s = 0; s < 4; ++s) {
            const uint32_t ku = Kp[(size_t)s*8192 + d_l*128 + kkp];
            const uint32_t vu = Vp[(size_t)s*8192 + d_l*128 + kkp];
            k0 += bf2f(ku << 16);
            k1 += bf2f(ku & 0xffff0000u);
            v0 += bf2f(vu << 16);
            v1 += bf2f(vu & 0xffff0000u);
        }
        const int kk0 = kkp*2;
        const float b0 = E_b[kk0], b1 = E_b[kk0 + 1];
        *(uint32_t*)(Vbf + ((size_t)(b*64 + dt*8 + d_l))*256 + kk0) =
            (uint32_t)f2bf(v0 + b0) | ((uint32_t)f2bf(v1 + b1) << 16);
        Kt[kk0][d_l]     = f2bf(k0 + b0);
        Kt[kk0 + 1][d_l] = f2bf(k1 + b1);
    }
    __syncthreads();

    // K transposed write: thread t = kk row, 8 d values (16B store)
    uint16_t* kout = Kbf + ((size_t)(b*256 + t))*64 + dt*8;
    s16x8 o0;
    #pragma unroll
    for (int i = 0; i < 8; ++i) o0[i] = (short)Kt[t][i];
    *(s16x8*)kout = o0;
}

// ---------------------------------------------------------------------------
// attn v6 (unchanged, verified).
// ---------------------------------------------------------------------------
__global__ __launch_bounds__(512, 4) void attn(
        const float* __restrict__ q,
        const uint16_t* __restrict__ Kbf, const uint16_t* __restrict__ Vbf,
        float* __restrict__ out) {
    const int wg   = blockIdx.x;
    const int st   = wg & 31;
    const int b    = wg >> 5;
    const int tid  = threadIdx.x;
    const int wave = tid >> 6;
    const int lane = tid & 63;
    const int l16  = lane & 15;
    const int grp  = lane >> 4;
    const int s0   = st * 128 + wave * 16;

    __shared__ __align__(16) uint16_t Klds[16384];
    __shared__ __align__(16) uint16_t Vlds[16384];

    const uint16_t* Kb = Kbf + (size_t)b * DK_ * D_;
    const uint16_t* Vb = Vbf + (size_t)b * D_ * DK_;

    #pragma unroll
    for (int i = 0; i < 4; ++i) {
        const int s  = wave*4 + i;
        const int nt = s >> 1, kt = s & 1;
        gload_lds16(Kb + (size_t)(nt*16 + l16) * D_ + kt*32 + grp*8, &Klds[s*512]);
    }
    #pragma unroll
    for (int i = 0; i < 4; ++i) {
        const int s   = wave*4 + i;
        const int kt2 = s >> 2, nt2 = s & 3;
        gload_lds16(Vb + (size_t)(nt2*16 + l16) * DK_ + kt2*32 + grp*8, &Vlds[s*512]);
    }

    s16x8 qb[2];
    {
        const float* qp = q + ((size_t)b * S_ + s0 + l16) * D_;
        #pragma unroll
        for (int kt = 0; kt < 2; ++kt) {
            const int d0 = kt*32 + grp*8;
            const float4 f0 = *(const float4*)(qp + d0);
            const float4 f1 = *(const float4*)(qp + d0 + 4);
            s16x8 a;
            a[0] = (short)f2bf(f0.x * 0.125f);
            a[1] = (short)f2bf(f0.y * 0.125f);
            a[2] = (short)f2bf(f0.z * 0.125f);
            a[3] = (short)f2bf(f0.w * 0.125f);
            a[4] = (short)f2bf(f1.x * 0.125f);
            a[5] = (short)f2bf(f1.y * 0.125f);
            a[6] = (short)f2bf(f1.z * 0.125f);
            a[7] = (short)f2bf(f1.w * 0.125f);
            qb[kt] = a;
        }
    }

    __syncthreads();

    f32x4 acc[16] = {};
    #pragma unroll
    for (int nt = 0; nt < 16; ++nt) {
        #pragma unroll
        for (int kt = 0; kt < 2; ++kt) {
            const s16x8 kf = *(const s16x8*)&Klds[(nt*2 + kt)*512 + lane*8];
            acc[nt] = __builtin_amdgcn_mfma_f32_16x16x32_bf16(kf, qb[kt], acc[nt], 0, 0, 0);
        }
    }

    float sm = 0.f;
    #pragma unroll
    for (int nt = 0; nt < 16; ++nt) {
        #pragma unroll
        for (int r = 0; r < 4; ++r) {
            const float e = __expf(acc[nt][r]);
            acc[nt][r] = e;
            sm += e;
        }
    }
    sm += __shfl_xor(sm, 16);
    sm += __shfl_xor(sm, 32);
    const float inv = 1.f / sm;

    uint32_t pk[16][2];
    #pragma unroll
    for (int nt = 0; nt < 16; ++nt) {
        pk[nt][0] = pk2(acc[nt][0], acc[nt][1]);
        pk[nt][1] = pk2(acc[nt][2], acc[nt][3]);
    }

    float invs[4];
    #pragma unroll
    for (int r = 0; r < 4; ++r) invs[r] = __shfl(inv, grp*4 + r);

    const int sl0 = (((grp << 1) + 0) & 3) * 16 + l16;
    const int sl1 = (((grp << 1) + 1) & 3) * 16 + l16;
    const bool lohalf = (grp < 2);

    f32x4 o[4] = {};
    #pragma unroll
    for (int kt2 = 0; kt2 < 8; ++kt2) {
        union { u32x4 wv; s16x8 h; } u;
        #pragma unroll
        for (int c = 0; c < 4; ++c) {
            const int tt = c & 1;
            const int sl = (c >> 1) ? sl1 : sl0;
            const uint32_t lo = (uint32_t)__shfl((int)pk[2*kt2 + 0][tt], sl);
            const uint32_t hi = (uint32_t)__shfl((int)pk[2*kt2 + 1][tt], sl);
            u.wv[c] = lohalf ? lo : hi;
        }
        #pragma unroll
        for (int nt2 = 0; nt2 < 4; ++nt2) {
            const s16x8 vf = *(const s16x8*)&Vlds[(kt2*4 + nt2)*512 + lane*8];
            o[nt2] = __builtin_amdgcn_mfma_f32_16x16x32_bf16(u.h, vf, o[nt2], 0, 0, 0);
        }
    }

    #pragma unroll
    for (int nt2 = 0; nt2 < 4; ++nt2)
        #pragma unroll
        for (int r = 0; r < 4; ++r)
            out[((size_t)b * S_ + s0 + grp*4 + r) * D_ + nt2*16 + l16] =
                o[nt2][r] * invs[r];
}

extern "C" void kernel_launch(void* const* d_in, const int* in_sizes, int n_in,
                              void* d_out, int out_size, void* d_ws, size_t ws_size,
                              hipStream_t stream) {
    const float* q   = (const float*)d_in[0];
    const float* k   = (const float*)d_in[1];
    const float* v   = (const float*)d_in[2];
    const float* E_w = (const float*)d_in[3];
    const float* E_b = (const float*)d_in[4];
    float* out = (float*)d_out;

    char* ws = (char*)d_ws;
    uint32_t* part = (uint32_t*)(ws);                     // 8 MB bf16-pairs
    uint16_t* Kbf  = (uint16_t*)(ws + (8u  << 20));       // 1 MB
    uint16_t* Vbf  = (uint16_t*)(ws + (9u  << 20));       // 1 MB
    uint16_t* EwbS = (uint16_t*)(ws + (10u << 20));       // 2 MB swizzled

    ewcvt<<<512, 256, 0, stream>>>(E_w, EwbS);
    proj_mfma<<<256, 256, 0, stream>>>(EwbS, k, v, part);
    bias_reduce<<<256, 256, 0, stream>>>(part, E_b, Kbf, Vbf);
    attn<<<1024, 512, 0, stream>>>(q, Kbf, Vbf, out);
}